// Round 1
// baseline (65.818 us; speedup 1.0000x reference)
//
#include <hip/hip_runtime.h>
#include <hip/hip_bf16.h>
#include <math.h>

// GAT layer: B=8, N=2048, D_IN=128, D_OUT=64, fp32.
// wh = h @ w; s1 = wh@a1; s2 = wh@a2;
// score(i,j) = leaky(s1[i]+s2[j]); softmax over adj>0 cols; out = coeffs @ wh.
// Sparse-aware single pass: adj (134 MB) read exactly once (memory floor ~21us).

#define GAT_B 8
#define GAT_N 2048
#define GAT_DIN 128
#define GAT_DOUT 64

// ---------------- Kernel 1: wh = h @ w, s1, s2 ----------------
// block = 256 threads = 4 waves; each wave computes one row's 64 outputs.
// w (128x64 fp32 = 32KB) staged in LDS; h rows staged in LDS (broadcast reads).
__global__ __launch_bounds__(256) void gat_wh_kernel(
    const float* __restrict__ h, const float* __restrict__ w,
    const float* __restrict__ a, float* __restrict__ wh,
    float* __restrict__ s1, float* __restrict__ s2) {
  __shared__ float w_lds[GAT_DIN * GAT_DOUT];   // 32 KB
  __shared__ float h_lds[4][GAT_DIN];           // 2 KB

  // cooperative load of w: 8192 floats = 2048 float4, 256 threads -> 8 each
  for (int t = threadIdx.x; t < (GAT_DIN * GAT_DOUT) / 4; t += 256)
    ((float4*)w_lds)[t] = ((const float4*)w)[t];

  const int lane = threadIdx.x & 63;
  const int wv = threadIdx.x >> 6;
  const float a1 = a[lane];
  const float a2 = a[GAT_DOUT + lane];

  const int ngroups = (GAT_B * GAT_N) / 4;  // 4096 groups of 4 rows
  for (int rg = blockIdx.x; rg < ngroups; rg += gridDim.x) {
    __syncthreads();  // protect h_lds from previous iteration's readers
    // load 4 rows (512 floats = 128 float4) cooperatively
    const float4* hsrc = (const float4*)(h + (size_t)rg * 4 * GAT_DIN);
    for (int t = threadIdx.x; t < (4 * GAT_DIN) / 4; t += 256)
      ((float4*)&h_lds[0][0])[t] = hsrc[t];
    __syncthreads();

    const int row = rg * 4 + wv;
    float acc = 0.f;
#pragma unroll 16
    for (int d = 0; d < GAT_DIN; ++d)
      acc = fmaf(h_lds[wv][d], w_lds[d * GAT_DOUT + lane], acc);

    wh[(size_t)row * GAT_DOUT + lane] = acc;

    float t1 = acc * a1, t2 = acc * a2;
#pragma unroll
    for (int off = 32; off >= 1; off >>= 1) {
      t1 += __shfl_xor(t1, off);
      t2 += __shfl_xor(t2, off);
    }
    if (lane == 0) { s1[row] = t1; s2[row] = t2; }
  }
}

// ---------------- Kernel 2: per-row online-softmax sparse aggregation -------
// One wave per output row (b,i). Streams the adj row with float4 loads,
// ballots for nonzeros, flash-style online softmax; lane f accumulates out[f].
__global__ __launch_bounds__(256) void gat_row_kernel(
    const float* __restrict__ adj, const float* __restrict__ wh,
    const float* __restrict__ s1, const float* __restrict__ s2,
    float* __restrict__ out) {
  const int lane = threadIdx.x & 63;
  const int wv = threadIdx.x >> 6;
  const int row = blockIdx.x * 4 + wv;       // [0, B*N)
  const int b = row >> 11;                   // row / 2048

  const float* adj_row = adj + (size_t)row * GAT_N;
  const float* s2b = s2 + (size_t)b * GAT_N;
  const float* whb = wh + (size_t)b * GAT_N * GAT_DOUT;
  const float s1i = s1[row];

  float m = -INFINITY;  // running max (wave-uniform)
  float l = 0.f;        // running denom (wave-uniform)
  float acc = 0.f;      // this lane's output feature

  for (int c = 0; c < GAT_N; c += 256) {
    const float4 av = *(const float4*)(adj_row + c + lane * 4);
    const float4 sv = *(const float4*)(s2b + c + lane * 4);
#pragma unroll
    for (int comp = 0; comp < 4; ++comp) {
      const float a_c = (comp == 0) ? av.x : (comp == 1) ? av.y
                       : (comp == 2) ? av.z : av.w;
      const float s_c = (comp == 0) ? sv.x : (comp == 1) ? sv.y
                       : (comp == 2) ? sv.z : sv.w;
      unsigned long long msk = __ballot(a_c > 0.f);
      while (msk) {
        const int bit = __builtin_ctzll(msk);
        msk &= msk - 1;
        const float s2j = __shfl(s_c, bit);
        const int j = c + bit * 4 + comp;
        float sc = s1i + s2j;
        sc = (sc >= 0.f) ? sc : 0.2f * sc;   // LeakyReLU(0.2)
        if (sc > m) {                        // wave-uniform branch
          const float r = __expf(m - sc);    // exp(-inf)=0 handles first hit
          acc *= r;
          l *= r;
          m = sc;
        }
        const float e = __expf(sc - m);
        l += e;
        acc = fmaf(e, whb[(size_t)j * GAT_DOUT + lane], acc);
      }
    }
  }
  out[(size_t)row * GAT_DOUT + lane] = acc / l;
}

extern "C" void kernel_launch(void* const* d_in, const int* in_sizes, int n_in,
                              void* d_out, int out_size, void* d_ws, size_t ws_size,
                              hipStream_t stream) {
  const float* h   = (const float*)d_in[0];  // (8, 2048, 128)
  const float* adj = (const float*)d_in[1];  // (8, 2048, 2048)
  const float* w   = (const float*)d_in[2];  // (128, 64)
  const float* a   = (const float*)d_in[3];  // (128, 1)
  float* out = (float*)d_out;                // (8, 2048, 64)

  // workspace layout
  const size_t rows = (size_t)GAT_B * GAT_N;           // 16384
  float* wh = (float*)d_ws;                            // rows*64 floats = 4 MB
  float* s1 = wh + rows * GAT_DOUT;                    // 64 KB
  float* s2 = s1 + rows;                               // 64 KB

  // Kernel 1: 1024 blocks x 256 thr, grid-stride over 4096 row-groups
  gat_wh_kernel<<<1024, 256, 0, stream>>>(h, w, a, wh, s1, s2);

  // Kernel 2: 4096 blocks x 256 thr (4 waves = 4 rows per block)
  gat_row_kernel<<<(GAT_B * GAT_N) / 4, 256, 0, stream>>>(adj, wh, s1, s2, out);
}

// Round 2
// 64.158 us; speedup vs baseline: 1.0259x; 1.0259x over previous
//
#include <hip/hip_runtime.h>
#include <hip/hip_bf16.h>
#include <math.h>

// GAT layer: B=8, N=2048, D_IN=128, D_OUT=64, fp32.
// wh = h @ w; s1 = wh@a1; s2 = wh@a2;
// score(i,j) = leaky(s1[i]+s2[j]); softmax over adj>0 cols; out = coeffs @ wh.
// Round 2: replace bit-serial neighbor loop with ballot+mbcnt compaction into
// LDS and a countable, pipelineable entry loop; chunk-granular online softmax.

#define GAT_B 8
#define GAT_N 2048
#define GAT_DIN 128
#define GAT_DOUT 64

// ---------------- Kernel 1: wh = h @ w, s1, s2 ----------------
__global__ __launch_bounds__(256) void gat_wh_kernel(
    const float* __restrict__ h, const float* __restrict__ w,
    const float* __restrict__ a, float* __restrict__ wh,
    float* __restrict__ s1, float* __restrict__ s2) {
  __shared__ float w_lds[GAT_DIN * GAT_DOUT];   // 32 KB
  __shared__ float h_lds[4][GAT_DIN];           // 2 KB

  for (int t = threadIdx.x; t < (GAT_DIN * GAT_DOUT) / 4; t += 256)
    ((float4*)w_lds)[t] = ((const float4*)w)[t];

  const int lane = threadIdx.x & 63;
  const int wv = threadIdx.x >> 6;
  const float a1 = a[lane];
  const float a2 = a[GAT_DOUT + lane];

  const int ngroups = (GAT_B * GAT_N) / 4;  // 4096 groups of 4 rows
  for (int rg = blockIdx.x; rg < ngroups; rg += gridDim.x) {
    __syncthreads();
    const float4* hsrc = (const float4*)(h + (size_t)rg * 4 * GAT_DIN);
    for (int t = threadIdx.x; t < (4 * GAT_DIN) / 4; t += 256)
      ((float4*)&h_lds[0][0])[t] = hsrc[t];
    __syncthreads();

    const int row = rg * 4 + wv;
    float acc = 0.f;
#pragma unroll 16
    for (int d = 0; d < GAT_DIN; ++d)
      acc = fmaf(h_lds[wv][d], w_lds[d * GAT_DOUT + lane], acc);

    wh[(size_t)row * GAT_DOUT + lane] = acc;

    float t1 = acc * a1, t2 = acc * a2;
#pragma unroll
    for (int off = 32; off >= 1; off >>= 1) {
      t1 += __shfl_xor(t1, off);
      t2 += __shfl_xor(t2, off);
    }
    if (lane == 0) { s1[row] = t1; s2[row] = t2; }
  }
}

// ---------------- Kernel 2: compacted sparse row aggregation ----------------
// One wave per row. Per 256-col chunk: ballot+mbcnt compaction of nonzero
// (j, score) pairs into LDS, wave max-reduce, ONE online-softmax rescale,
// then a countable entry loop (dual accumulators) over ~5 entries/chunk.
__global__ __launch_bounds__(256) void gat_row_kernel(
    const float* __restrict__ adj, const float* __restrict__ wh,
    const float* __restrict__ s1, const float* __restrict__ s2,
    float* __restrict__ out) {
  __shared__ unsigned int idx_l[4][256];  // 4 KB
  __shared__ float sc_l[4][256];          // 4 KB

  const int lane = threadIdx.x & 63;
  const int wv = threadIdx.x >> 6;
  const int row = blockIdx.x * 4 + wv;       // [0, B*N)
  const int b = row >> 11;                   // row / 2048

  const float* adj_row = adj + (size_t)row * GAT_N;
  const float* s2b = s2 + (size_t)b * GAT_N;
  const float* whb = wh + (size_t)b * GAT_N * GAT_DOUT;
  const float s1i = s1[row];
  unsigned int* my_idx = idx_l[wv];
  float* my_sc = sc_l[wv];

  float m = -1e30f;                // running max (wave-uniform)
  float l0 = 0.f, l1 = 0.f;        // running denom halves
  float acc0 = 0.f, acc1 = 0.f;    // this lane's output feature halves

  for (int c = 0; c < GAT_N; c += 256) {
    const float4 av = *(const float4*)(adj_row + c + lane * 4);
    const float4 sv = *(const float4*)(s2b + c + lane * 4);
    int base = 0;
    float cmax = -1e30f;
#pragma unroll
    for (int comp = 0; comp < 4; ++comp) {
      const float a_c = (comp == 0) ? av.x : (comp == 1) ? av.y
                       : (comp == 2) ? av.z : av.w;
      const float s_c = (comp == 0) ? sv.x : (comp == 1) ? sv.y
                       : (comp == 2) ? sv.z : sv.w;
      float sc = s1i + s_c;
      sc = (sc >= 0.f) ? sc : 0.2f * sc;   // LeakyReLU(0.2)
      const bool pred = a_c > 0.f;
      const unsigned long long msk = __ballot(pred);
      if (msk) {
        const int prefix = __builtin_amdgcn_mbcnt_hi(
            (unsigned)(msk >> 32),
            __builtin_amdgcn_mbcnt_lo((unsigned)msk, 0u));
        if (pred) {
          my_idx[base + prefix] = (unsigned)(c + lane * 4 + comp);
          my_sc[base + prefix] = sc;
          cmax = fmaxf(cmax, sc);
        }
        base += (int)__popcll(msk);
      }
    }
    if (base == 0) continue;  // wave-uniform

    // wave max-reduce of this chunk's scores
#pragma unroll
    for (int off = 32; off >= 1; off >>= 1)
      cmax = fmaxf(cmax, __shfl_xor(cmax, off));

    // one online-softmax rescale per chunk
    const float newm = fmaxf(m, cmax);
    const float r = __expf(m - newm);  // first chunk: exp(-inf) = 0
    l0 *= r; l1 *= r; acc0 *= r; acc1 *= r;
    m = newm;

    // countable entry loop, dual accumulators for ILP
    int t = 0;
    for (; t + 2 <= base; t += 2) {
      const float e0 = __expf(my_sc[t] - m);
      const float e1 = __expf(my_sc[t + 1] - m);
      const unsigned j0 = my_idx[t];
      const unsigned j1 = my_idx[t + 1];
      l0 += e0;
      l1 += e1;
      acc0 = fmaf(e0, whb[(size_t)j0 * GAT_DOUT + lane], acc0);
      acc1 = fmaf(e1, whb[(size_t)j1 * GAT_DOUT + lane], acc1);
    }
    if (t < base) {
      const float e0 = __expf(my_sc[t] - m);
      const unsigned j0 = my_idx[t];
      l0 += e0;
      acc0 = fmaf(e0, whb[(size_t)j0 * GAT_DOUT + lane], acc0);
    }
  }
  out[(size_t)row * GAT_DOUT + lane] = (acc0 + acc1) / (l0 + l1);
}

extern "C" void kernel_launch(void* const* d_in, const int* in_sizes, int n_in,
                              void* d_out, int out_size, void* d_ws, size_t ws_size,
                              hipStream_t stream) {
  const float* h   = (const float*)d_in[0];  // (8, 2048, 128)
  const float* adj = (const float*)d_in[1];  // (8, 2048, 2048)
  const float* w   = (const float*)d_in[2];  // (128, 64)
  const float* a   = (const float*)d_in[3];  // (128, 1)
  float* out = (float*)d_out;                // (8, 2048, 64)

  const size_t rows = (size_t)GAT_B * GAT_N;           // 16384
  float* wh = (float*)d_ws;                            // rows*64 floats = 4 MB
  float* s1 = wh + rows * GAT_DOUT;                    // 64 KB
  float* s2 = s1 + rows;                               // 64 KB

  gat_wh_kernel<<<1024, 256, 0, stream>>>(h, w, a, wh, s1, s2);
  gat_row_kernel<<<(GAT_B * GAT_N) / 4, 256, 0, stream>>>(adj, wh, s1, s2, out);
}

// Round 3
// 60.176 us; speedup vs baseline: 1.0937x; 1.0662x over previous
//
#include <hip/hip_runtime.h>
#include <hip/hip_bf16.h>
#include <math.h>

// GAT layer: B=8, N=2048, D_IN=128, D_OUT=64, fp32.
// Round 3: one BLOCK per row (4 waves x 512 cols) -> 2 adj loads in flight per
// wave, s2 staged in LDS, plain two-pass block softmax (no online rescale).

#define GAT_B 8
#define GAT_N 2048
#define GAT_DIN 128
#define GAT_DOUT 64

// ---------------- Kernel 1: wh = h @ w, s1, s2 ----------------
__global__ __launch_bounds__(256) void gat_wh_kernel(
    const float* __restrict__ h, const float* __restrict__ w,
    const float* __restrict__ a, float* __restrict__ wh,
    float* __restrict__ s1, float* __restrict__ s2) {
  __shared__ float w_lds[GAT_DIN * GAT_DOUT];   // 32 KB
  __shared__ float h_lds[4][GAT_DIN];           // 2 KB

  for (int t = threadIdx.x; t < (GAT_DIN * GAT_DOUT) / 4; t += 256)
    ((float4*)w_lds)[t] = ((const float4*)w)[t];

  const int lane = threadIdx.x & 63;
  const int wv = threadIdx.x >> 6;
  const float a1 = a[lane];
  const float a2 = a[GAT_DOUT + lane];

  const int ngroups = (GAT_B * GAT_N) / 4;  // 4096 groups of 4 rows
  for (int rg = blockIdx.x; rg < ngroups; rg += gridDim.x) {
    __syncthreads();
    const float4* hsrc = (const float4*)(h + (size_t)rg * 4 * GAT_DIN);
    for (int t = threadIdx.x; t < (4 * GAT_DIN) / 4; t += 256)
      ((float4*)&h_lds[0][0])[t] = hsrc[t];
    __syncthreads();

    const int row = rg * 4 + wv;
    float acc = 0.f;
#pragma unroll 16
    for (int d = 0; d < GAT_DIN; ++d)
      acc = fmaf(h_lds[wv][d], w_lds[d * GAT_DOUT + lane], acc);

    wh[(size_t)row * GAT_DOUT + lane] = acc;

    float t1 = acc * a1, t2 = acc * a2;
#pragma unroll
    for (int off = 32; off >= 1; off >>= 1) {
      t1 += __shfl_xor(t1, off);
      t2 += __shfl_xor(t2, off);
    }
    if (lane == 0) { s1[row] = t1; s2[row] = t2; }
  }
}

// ---------------- Kernel 2: one block per row, two-pass block softmax -------
__global__ __launch_bounds__(256) void gat_row_kernel(
    const float* __restrict__ adj, const float* __restrict__ wh,
    const float* __restrict__ s1, const float* __restrict__ s2,
    float* __restrict__ out) {
  __shared__ float s2_lds[GAT_N];              // 8 KB
  __shared__ float sc_l[4][512];               // 8 KB
  __shared__ unsigned short idx_l[4][512];     // 4 KB
  __shared__ float acc_l[4][GAT_DOUT];         // 1 KB
  __shared__ float wmax[4];
  __shared__ float wsum[4];

  const int lane = threadIdx.x & 63;
  const int wv = threadIdx.x >> 6;
  const int row = blockIdx.x;                  // [0, B*N)
  const int b = row >> 11;                     // row / 2048

  const float* adj_row = adj + (size_t)row * GAT_N;
  const float* s2b = s2 + (size_t)b * GAT_N;
  const float* whb = wh + (size_t)b * GAT_N * GAT_DOUT;
  const float s1i = s1[row];

  // Issue both adj chunk loads up-front (2 x 1KB/wave in flight).
  const int c0 = wv * 512;
  const float4 av0 = *(const float4*)(adj_row + c0 + lane * 4);
  const float4 av1 = *(const float4*)(adj_row + c0 + 256 + lane * 4);

  // Cooperative stage of the s2 row: 2048 floats = 512 float4, 2 per thread.
  {
    const float4* src = (const float4*)s2b;
    float4* dst = (float4*)s2_lds;
    dst[threadIdx.x] = src[threadIdx.x];
    dst[threadIdx.x + 256] = src[threadIdx.x + 256];
  }
  __syncthreads();

  // Phase 1: ballot+mbcnt compaction of nonzero (j, score) into this wave's
  // LDS list; track local max. Capacity 512 == this wave's col count (safe).
  int base = 0;
  float cmax = -1e30f;
  auto compact = [&](float a_c, int j) {
    const bool pred = a_c > 0.f;
    const unsigned long long msk = __ballot(pred);
    if (msk) {  // wave-uniform
      const int prefix = __builtin_amdgcn_mbcnt_hi(
          (unsigned)(msk >> 32),
          __builtin_amdgcn_mbcnt_lo((unsigned)msk, 0u));
      if (pred) {
        float sc = s1i + s2_lds[j];
        sc = (sc >= 0.f) ? sc : 0.2f * sc;   // LeakyReLU(0.2)
        sc_l[wv][base + prefix] = sc;
        idx_l[wv][base + prefix] = (unsigned short)j;
        cmax = fmaxf(cmax, sc);
      }
      base += (int)__popcll(msk);
    }
  };
  compact(av0.x, c0 + lane * 4 + 0);
  compact(av0.y, c0 + lane * 4 + 1);
  compact(av0.z, c0 + lane * 4 + 2);
  compact(av0.w, c0 + lane * 4 + 3);
  compact(av1.x, c0 + 256 + lane * 4 + 0);
  compact(av1.y, c0 + 256 + lane * 4 + 1);
  compact(av1.z, c0 + 256 + lane * 4 + 2);
  compact(av1.w, c0 + 256 + lane * 4 + 3);

#pragma unroll
  for (int off = 32; off >= 1; off >>= 1)
    cmax = fmaxf(cmax, __shfl_xor(cmax, off));
  if (lane == 0) wmax[wv] = cmax;
  __syncthreads();

  // Block max (every row has a self-loop, so at least one wave is nonempty).
  const float m = fmaxf(fmaxf(wmax[0], wmax[1]), fmaxf(wmax[2], wmax[3]));

  // Phase 2: single exp+gather pass, dual accumulators for ILP.
  float l0 = 0.f, l1 = 0.f, acc0 = 0.f, acc1 = 0.f;
  const float* scw = sc_l[wv];
  const unsigned short* idxw = idx_l[wv];
  int t = 0;
  for (; t + 2 <= base; t += 2) {
    const float e0 = __expf(scw[t] - m);
    const float e1 = __expf(scw[t + 1] - m);
    const int j0 = idxw[t];
    const int j1 = idxw[t + 1];
    l0 += e0;
    l1 += e1;
    acc0 = fmaf(e0, whb[(size_t)j0 * GAT_DOUT + lane], acc0);
    acc1 = fmaf(e1, whb[(size_t)j1 * GAT_DOUT + lane], acc1);
  }
  if (t < base) {
    const float e0 = __expf(scw[t] - m);
    const int j0 = idxw[t];
    l0 += e0;
    acc0 = fmaf(e0, whb[(size_t)j0 * GAT_DOUT + lane], acc0);
  }

  acc_l[wv][lane] = acc0 + acc1;
  if (lane == 0) wsum[wv] = l0 + l1;   // l is wave-uniform
  __syncthreads();

  // Block combine + write (wave 0 only; 256B coalesced store).
  if (wv == 0) {
    const float acc = acc_l[0][lane] + acc_l[1][lane] +
                      acc_l[2][lane] + acc_l[3][lane];
    const float l = wsum[0] + wsum[1] + wsum[2] + wsum[3];
    out[(size_t)row * GAT_DOUT + lane] = acc / l;
  }
}

extern "C" void kernel_launch(void* const* d_in, const int* in_sizes, int n_in,
                              void* d_out, int out_size, void* d_ws, size_t ws_size,
                              hipStream_t stream) {
  const float* h   = (const float*)d_in[0];  // (8, 2048, 128)
  const float* adj = (const float*)d_in[1];  // (8, 2048, 2048)
  const float* w   = (const float*)d_in[2];  // (128, 64)
  const float* a   = (const float*)d_in[3];  // (128, 1)
  float* out = (float*)d_out;                // (8, 2048, 64)

  const size_t rows = (size_t)GAT_B * GAT_N;           // 16384
  float* wh = (float*)d_ws;                            // rows*64 floats = 4 MB
  float* s1 = wh + rows * GAT_DOUT;                    // 64 KB
  float* s2 = s1 + rows;                               // 64 KB

  gat_wh_kernel<<<1024, 256, 0, stream>>>(h, w, a, wh, s1, s2);
  gat_row_kernel<<<GAT_B * GAT_N, 256, 0, stream>>>(adj, wh, s1, s2, out);
}